// Round 8
// baseline (214.954 us; speedup 1.0000x reference)
//
#include <hip/hip_runtime.h>

#define H 64
#define NPIX 65536
#define LBATCH 8
#define LC 24
#define S_CHUNKS 64
#define PB 1024            // pixels per block
#define EPSF 1e-6f
#define LN2_50 34.6573590f // 50 * ln(2): 50*(ln a - ln b) = LN2_50*(log2 a - log2 b)

// ws: partials [8 l][64 chunk][3 c][4096] + per-(lc,seg) sums [LC*16]
#define WS_PART ((size_t)LBATCH * S_CHUNKS * 3 * H * H)
#define NEED_WS ((WS_PART + LC * 16) * 4)

typedef _Float16 h8 __attribute__((ext_vector_type(8)));   // MFMA operand
typedef _Float16 h4 __attribute__((ext_vector_type(4)));
typedef _Float16 h2 __attribute__((ext_vector_type(2)));
typedef short    s2 __attribute__((ext_vector_type(2)));
typedef float f32x16 __attribute__((ext_vector_type(16)));
union H8p { h8 v8; h2 h[4]; };

#if __has_builtin(__builtin_elementwise_fma)
#define FMA2(a, b, c) __builtin_elementwise_fma((a), (b), (c))
#else
#define FMA2(a, b, c) ((a) * (b) + (c))
#endif

// Full-rate packed-fp16 eval of 1/(1+d^2): int-magic seed + 2 packed Newton
// steps. Zero trans-pipe ops. x clamped to 16384 (tail values <=6e-5).
static __device__ __forceinline__ h2 kev2(h2 u2, h2 o2, h2 one2, h2 two2,
                                          h2 clamp2, s2 magic2) {
    const h2 d  = u2 - o2;
    const h2 xx = __builtin_elementwise_min(FMA2(d, d, one2), clamp2);
    h2 y = __builtin_bit_cast(h2, (s2)(magic2 - __builtin_bit_cast(s2, xx)));
    y = y * FMA2(-xx, y, two2);
    y = y * FMA2(-xx, y, two2);
    return y;
}

#define MFMA(a, b, acc) __builtin_amdgcn_mfma_f32_32x32x16_f16((a), (b), (acc), 0, 0, 0)

__global__ __launch_bounds__(256) void hist_zero(float* __restrict__ out) {
    out[blockIdx.x * 256 + threadIdx.x] = 0.0f;
}

// One block per (l, 1024-px chunk) computes ALL THREE channel histograms via
// the log-difference symmetry: D01=lg0-lg1, D02=lg0-lg2, D12=lg1-lg2;
// off[63-i] = -off[i] so K(-d)[u] = K(d)[63-u]. Three gemms on unreversed
// operands: G0=sum wK01(x)K02, G1=sum wK01(x)K12, G2=sum wK02(x)K12; then
// c0=G0, c1[u,v]=G1[63-u,v], c2[u,v]=G2[63-u,63-v] (flips applied at the LDS
// merge). 12 acc tiles (192 acc regs) -> launch_bounds(256,1) so the
// allocator can spread out (~300 unified regs, 1 wave/SIMD, ILP-driven).
__global__ __launch_bounds__(256, 1) void hist_main(const float* __restrict__ x,
                                                    float* __restrict__ dst,
                                                    int atomic_mode) {
    __shared__ _Float16 sD01[PB];
    __shared__ _Float16 sD02[PB];
    __shared__ _Float16 sD12[PB];
    __shared__ _Float16 sWw[PB];
    __shared__ float sH[3 * H * H];          // 48 KB

    const int tid  = threadIdx.x;
    const int wv   = tid >> 6;
    const int lane = tid & 63;
    const int hf   = lane >> 5;
    const int ln   = lane & 31;
    const int l    = blockIdx.y;             // sample
    const int chnk = blockIdx.x;             // pixel chunk

    #pragma unroll
    for (int r = 0; r < 12; r++)
        *(float4*)&sH[(r * 256 + tid) * 4] = make_float4(0.f, 0.f, 0.f, 0.f);

    const float* __restrict__ x0p = x + (l * 3 + 0) * NPIX;
    const float* __restrict__ x1p = x + (l * 3 + 1) * NPIX;
    const float* __restrict__ x2p = x + (l * 3 + 2) * NPIX;
    const int base = chnk * PB;

    // ---- Phase 1: prep 4 px/thread, store fp16 D01/D02/D12/w ----
    {
        const int ploc = tid * 4;
        const float4 r0 = *(const float4*)&x0p[base + ploc];
        const float4 r1 = *(const float4*)&x1p[base + ploc];
        const float4 r2 = *(const float4*)&x2p[base + ploc];
        float4 A4, B4, C4, W4;
        #define PREP(E) { \
            const float v0 = fminf(fmaxf(r0.E, 0.0f), 1.0f); \
            const float v1 = fminf(fmaxf(r1.E, 0.0f), 1.0f); \
            const float v2 = fminf(fmaxf(r2.E, 0.0f), 1.0f); \
            W4.E = __builtin_amdgcn_sqrtf(fmaf(v0, v0, fmaf(v1, v1, fmaf(v2, v2, EPSF)))); \
            const float lg0 = __builtin_amdgcn_logf(v0 + EPSF); \
            const float lg1 = __builtin_amdgcn_logf(v1 + EPSF); \
            const float lg2 = __builtin_amdgcn_logf(v2 + EPSF); \
            A4.E = LN2_50 * (lg0 - lg1); \
            B4.E = LN2_50 * (lg0 - lg2); \
            C4.E = LN2_50 * (lg1 - lg2); }
        PREP(x) PREP(y) PREP(z) PREP(w)
        #undef PREP
        *(h4*)&sD01[ploc] = h4{(_Float16)A4.x, (_Float16)A4.y, (_Float16)A4.z, (_Float16)A4.w};
        *(h4*)&sD02[ploc] = h4{(_Float16)B4.x, (_Float16)B4.y, (_Float16)B4.z, (_Float16)B4.w};
        *(h4*)&sD12[ploc] = h4{(_Float16)C4.x, (_Float16)C4.y, (_Float16)C4.z, (_Float16)C4.w};
        *(h4*)&sWw[ploc]  = h4{(_Float16)W4.x, (_Float16)W4.y, (_Float16)W4.z, (_Float16)W4.w};
    }
    __syncthreads();

    // ---- Phase 2: 16 K-steps over this wave's 256-px slice, 12 MFMA each ----
    const float step50 = 50.0f * (6.0f / 63.0f);
    const float ou0 = -150.0f + step50 * (float)ln;
    const float ou1 = ou0 + step50 * 32.0f;
    const h2 o0_2 = {(_Float16)ou0, (_Float16)ou0};
    const h2 o1_2 = {(_Float16)ou1, (_Float16)ou1};
    const h2 one2   = {(_Float16)1.0f, (_Float16)1.0f};
    const h2 two2   = {(_Float16)2.0f, (_Float16)2.0f};
    const h2 clamp2 = {(_Float16)16384.0f, (_Float16)16384.0f};
    const s2 magic2 = {(short)0x779A, (short)0x779A};

    f32x16 g0_00, g0_01, g0_10, g0_11;
    f32x16 g1_00, g1_01, g1_10, g1_11;
    f32x16 g2_00, g2_01, g2_10, g2_11;
    #pragma unroll
    for (int i = 0; i < 16; i++) {
        g0_00[i] = 0.f; g0_01[i] = 0.f; g0_10[i] = 0.f; g0_11[i] = 0.f;
        g1_00[i] = 0.f; g1_01[i] = 0.f; g1_10[i] = 0.f; g1_11[i] = 0.f;
        g2_00[i] = 0.f; g2_01[i] = 0.f; g2_10[i] = 0.f; g2_11[i] = 0.f;
    }

    const int wbase = wv * 256;
    // manual next-K prefetch (1 wave/SIMD: ILP must hide the LDS latency)
    H8p d01, d02, d12, ww;
    {
        const int kb = wbase + hf * 8;
        d01.v8 = *(const h8*)&sD01[kb];
        d02.v8 = *(const h8*)&sD02[kb];
        d12.v8 = *(const h8*)&sD12[kb];
        ww.v8  = *(const h8*)&sWw[kb];
    }
    #pragma unroll 1
    for (int ks = 0; ks < 16; ks++) {
        const int kbn = wbase + ((ks + 1) & 15) * 16 + hf * 8;  // wraps: harmless
        H8p n01, n02, n12, nww;
        n01.v8 = *(const h8*)&sD01[kbn];
        n02.v8 = *(const h8*)&sD02[kbn];
        n12.v8 = *(const h8*)&sD12[kbn];
        nww.v8 = *(const h8*)&sWw[kbn];

        H8p a01t0, a01t1, b02t0, b02t1, a02t0, a02t1, b12t0, b12t1;
        #pragma unroll
        for (int q = 0; q < 4; q++) {
            const h2 k01t0 = kev2(d01.h[q], o0_2, one2, two2, clamp2, magic2);
            const h2 k01t1 = kev2(d01.h[q], o1_2, one2, two2, clamp2, magic2);
            a01t0.h[q] = ww.h[q] * k01t0;
            a01t1.h[q] = ww.h[q] * k01t1;
            b02t0.h[q] = kev2(d02.h[q], o0_2, one2, two2, clamp2, magic2);
            b02t1.h[q] = kev2(d02.h[q], o1_2, one2, two2, clamp2, magic2);
            a02t0.h[q] = ww.h[q] * b02t0.h[q];
            a02t1.h[q] = ww.h[q] * b02t1.h[q];
            b12t0.h[q] = kev2(d12.h[q], o0_2, one2, two2, clamp2, magic2);
            b12t1.h[q] = kev2(d12.h[q], o1_2, one2, two2, clamp2, magic2);
        }
        g0_00 = MFMA(a01t0.v8, b02t0.v8, g0_00);
        g0_01 = MFMA(a01t0.v8, b02t1.v8, g0_01);
        g0_10 = MFMA(a01t1.v8, b02t0.v8, g0_10);
        g0_11 = MFMA(a01t1.v8, b02t1.v8, g0_11);
        g1_00 = MFMA(a01t0.v8, b12t0.v8, g1_00);
        g1_01 = MFMA(a01t0.v8, b12t1.v8, g1_01);
        g1_10 = MFMA(a01t1.v8, b12t0.v8, g1_10);
        g1_11 = MFMA(a01t1.v8, b12t1.v8, g1_11);
        g2_00 = MFMA(a02t0.v8, b12t0.v8, g2_00);
        g2_01 = MFMA(a02t0.v8, b12t1.v8, g2_01);
        g2_10 = MFMA(a02t1.v8, b12t0.v8, g2_10);
        g2_11 = MFMA(a02t1.v8, b12t1.v8, g2_11);
        d01 = n01; d02 = n02; d12 = n12; ww = nww;
    }

    // merge with flips (C/D layout: col=ln, row=(r&3)+8*(r>>2)+4*hf)
    #pragma unroll
    for (int r = 0; r < 16; r++) {
        const int row = (r & 3) + 8 * (r >> 2) + 4 * hf;   // 0..31 tile-local
        float* __restrict__ h0 = &sH[0];
        float* __restrict__ h1 = &sH[H * H];
        float* __restrict__ h2s = &sH[2 * H * H];
        // c0 = G0 direct
        atomicAdd(&h0[row * 64 + ln],              g0_00[r]);
        atomicAdd(&h0[row * 64 + 32 + ln],         g0_01[r]);
        atomicAdd(&h0[(row + 32) * 64 + ln],       g0_10[r]);
        atomicAdd(&h0[(row + 32) * 64 + 32 + ln],  g0_11[r]);
        // c1[u,v] = G1[63-u, v]
        atomicAdd(&h1[(63 - row) * 64 + ln],             g1_00[r]);
        atomicAdd(&h1[(63 - row) * 64 + 32 + ln],        g1_01[r]);
        atomicAdd(&h1[(31 - row) * 64 + ln],             g1_10[r]);
        atomicAdd(&h1[(31 - row) * 64 + 32 + ln],        g1_11[r]);
        // c2[u,v] = G2[63-u, 63-v]
        atomicAdd(&h2s[(63 - row) * 64 + (63 - ln)],     g2_00[r]);
        atomicAdd(&h2s[(63 - row) * 64 + (31 - ln)],     g2_01[r]);
        atomicAdd(&h2s[(31 - row) * 64 + (63 - ln)],     g2_10[r]);
        atomicAdd(&h2s[(31 - row) * 64 + (31 - ln)],     g2_11[r]);
    }
    __syncthreads();

    if (atomic_mode == 0) {
        // partial[(l*64+chnk)*3*4096 ...], coalesced float4 stores
        float* __restrict__ g = dst + (size_t)(l * S_CHUNKS + chnk) * 3 * H * H;
        #pragma unroll
        for (int r = 0; r < 12; r++) {
            const int i = (r * 256 + tid) * 4;
            *(float4*)&g[i] = *(const float4*)&sH[i];
        }
    } else {
        float* __restrict__ g = dst + (size_t)l * 3 * H * H;
        #pragma unroll
        for (int r = 0; r < 12; r++) {
            const int i = r * 256 + tid;
            unsafeAtomicAdd(&g[i], sH[i]);
        }
    }
}

// out[lc][i] = sum of 64 chunk-partials; also per-(lc,seg) sums for norm
__global__ __launch_bounds__(256) void hist_reduce(const float* __restrict__ part,
                                                   float* __restrict__ out,
                                                   float* __restrict__ sums) {
    const int lc  = blockIdx.x >> 4;         // l*3+c
    const int seg = blockIdx.x & 15;
    const int l   = lc / 3;
    const int c   = lc - 3 * l;
    const int off = seg * 256 + threadIdx.x;
    float s = 0.0f;
    #pragma unroll 4
    for (int sc = 0; sc < S_CHUNKS; sc++)
        s += part[((size_t)(l * S_CHUNKS + sc) * 3 + c) * (H * H) + off];
    out[lc * (H * H) + off] = s;
    float t = s;
    #pragma unroll
    for (int o = 32; o > 0; o >>= 1) t += __shfl_down(t, o, 64);
    __shared__ float ps[4];
    if ((threadIdx.x & 63) == 0) ps[threadIdx.x >> 6] = t;
    __syncthreads();
    if (threadIdx.x == 0) sums[blockIdx.x] = (ps[0] + ps[1]) + (ps[2] + ps[3]);
}

// wide normalize: sample l's total = sum of its 48 (lc,seg) sums
__global__ __launch_bounds__(256) void hist_norm(float* __restrict__ out,
                                                 const float* __restrict__ sums) {
    const int i = blockIdx.x * 256 + threadIdx.x;
    const int l = blockIdx.x / 48;
    float T = 0.0f;
    #pragma unroll
    for (int k = 0; k < 48; k++) T += sums[l * 48 + k];
    out[i] = out[i] / (T + EPSF);
}

// fallback finish (atomic path): one block per sample
__global__ __launch_bounds__(256) void hist_finish(float* __restrict__ out) {
    const int l = blockIdx.x;
    float* __restrict__ p = out + l * 3 * H * H;
    float s = 0.0f;
    #pragma unroll
    for (int it = 0; it < 12; it++) {
        const float4 v = *(const float4*)&p[(it * 256 + threadIdx.x) * 4];
        s += (v.x + v.y) + (v.z + v.w);
    }
    #pragma unroll
    for (int off = 32; off > 0; off >>= 1) s += __shfl_down(s, off, 64);
    __shared__ float ps[4];
    if ((threadIdx.x & 63) == 0) ps[threadIdx.x >> 6] = s;
    __syncthreads();
    const float T = (ps[0] + ps[1]) + (ps[2] + ps[3]);
    const float inv = 1.0f / (T + EPSF);
    #pragma unroll
    for (int it = 0; it < 12; it++) {
        float4 v = *(const float4*)&p[(it * 256 + threadIdx.x) * 4];
        v.x *= inv; v.y *= inv; v.z *= inv; v.w *= inv;
        *(float4*)&p[(it * 256 + threadIdx.x) * 4] = v;
    }
}

extern "C" void kernel_launch(void* const* d_in, const int* in_sizes, int n_in,
                              void* d_out, int out_size, void* d_ws, size_t ws_size,
                              hipStream_t stream) {
    const float* x = (const float*)d_in[0];
    float* out = (float*)d_out;
    float* ws  = (float*)d_ws;

    if (ws_size >= NEED_WS) {
        float* sums = ws + WS_PART;
        hipLaunchKernelGGL(hist_main,   dim3(S_CHUNKS, LBATCH),  dim3(256), 0, stream, x, ws, 0);
        hipLaunchKernelGGL(hist_reduce, dim3(LC * 16),           dim3(256), 0, stream, ws, out, sums);
        hipLaunchKernelGGL(hist_norm,   dim3(LC * H * H / 256),  dim3(256), 0, stream, out, sums);
    } else {
        hipLaunchKernelGGL(hist_zero,   dim3(LC * H * H / 256),  dim3(256), 0, stream, out);
        hipLaunchKernelGGL(hist_main,   dim3(S_CHUNKS, LBATCH),  dim3(256), 0, stream, x, out, 1);
        hipLaunchKernelGGL(hist_finish, dim3(LBATCH),            dim3(256), 0, stream, out);
    }
}

// Round 9
// 177.824 us; speedup vs baseline: 1.2088x; 1.2088x over previous
//
#include <hip/hip_runtime.h>

#define H 64
#define NPIX 65536
#define LBATCH 8
#define LC 24
#define N_CHUNKS 8
#define PB 8192            // pixels per block
#define EPSF 1e-6f
#define LN2_50 34.6573590f // 50 * ln(2): 50*(ln a - ln b) = LN2_50*(log2 a - log2 b)

// ws: partials [N_CHUNKS][LC][H*H] + per-(lc,seg) sums [LC*16]
#define WS_PART ((size_t)N_CHUNKS * LC * H * H)
#define NEED_WS ((WS_PART + LC * 16) * 4)

typedef _Float16 h8 __attribute__((ext_vector_type(8)));   // MFMA operand
typedef _Float16 h4 __attribute__((ext_vector_type(4)));
typedef _Float16 h2 __attribute__((ext_vector_type(2)));
typedef short    s2 __attribute__((ext_vector_type(2)));
typedef float f32x16 __attribute__((ext_vector_type(16)));
union H8p { h8 v8; h2 h[4]; };

#if __has_builtin(__builtin_elementwise_fma)
#define FMA2(a, b, c) __builtin_elementwise_fma((a), (b), (c))
#else
#define FMA2(a, b, c) ((a) * (b) + (c))
#endif

// Full-rate packed-fp16 eval of 1/(1+d^2): int-magic seed + 2 packed Newton
// steps. Zero trans-pipe ops. x clamped to 16384 (tail values <=6e-5).
static __device__ __forceinline__ h2 kev2(h2 u2, h2 o2, h2 one2, h2 two2,
                                          h2 clamp2, s2 magic2) {
    const h2 d  = u2 - o2;
    const h2 xx = __builtin_elementwise_min(FMA2(d, d, one2), clamp2);
    h2 y = __builtin_bit_cast(h2, (s2)(magic2 - __builtin_bit_cast(s2, xx)));
    y = y * FMA2(-xx, y, two2);
    y = y * FMA2(-xx, y, two2);
    return y;
}

#define MFMA(a, b, acc) __builtin_amdgcn_mfma_f32_32x32x16_f16((a), (b), (acc), 0, 0, 0)

__global__ __launch_bounds__(256) void hist_zero(float* __restrict__ out) {
    out[blockIdx.x * 256 + threadIdx.x] = 0.0f;
}

// ONE dispatch round: 192 blocks x 1024 threads (16 waves = 4 waves/SIMD for
// TLP at fixed low DVFS clock). Block = (lc, 8192-px chunk). Phase 1: stage
// fp16 U50/V50/w (48 KB). Phase 2: each wave runs 32 K-steps over its 512-px
// slice (3 broadcast ds_read_b128 -> 16 kev2 -> 4 mfma_f32_32x32x16_f16,
// 4 acc tiles = 64 acc regs; ~112 unified regs fits 128/wave cap, no spill).
// Epilogue: 16-wave LDS merge, plain coalesced partial store (3.1 MB total).
__global__ __launch_bounds__(1024) void hist_main(const float* __restrict__ x,
                                                  float* __restrict__ dst,
                                                  int atomic_mode) {
    __shared__ _Float16 sUh[PB];
    __shared__ _Float16 sVh[PB];
    __shared__ _Float16 sWh[PB];
    __shared__ float sHist[H * H];

    const int tid  = threadIdx.x;
    const int wv   = tid >> 6;               // 0..15
    const int lane = tid & 63;
    const int hf   = lane >> 5;
    const int ln   = lane & 31;
    const int lc   = blockIdx.y;
    const int l    = lc / 3;
    const int c    = lc - 3 * l;

    // zero block histogram (1024 threads x 1 float4)
    *(float4*)&sHist[tid * 4] = make_float4(0.f, 0.f, 0.f, 0.f);

    const float* __restrict__ x0p = x + (l * 3 + 0) * NPIX;
    const float* __restrict__ x1p = x + (l * 3 + 1) * NPIX;
    const float* __restrict__ x2p = x + (l * 3 + 2) * NPIX;
    const int base = blockIdx.x * PB;

    // ---- Phase 1: prep 8 px/thread (2 passes of float4), store fp16 ----
    #pragma unroll
    for (int pass = 0; pass < 2; pass++) {
        const int ploc = pass * 4096 + tid * 4;
        const float4 r0 = *(const float4*)&x0p[base + ploc];
        const float4 r1 = *(const float4*)&x1p[base + ploc];
        const float4 r2 = *(const float4*)&x2p[base + ploc];
        float4 U4, V4, W4;
        #define PREP(E) { \
            const float v0 = fminf(fmaxf(r0.E, 0.0f), 1.0f); \
            const float v1 = fminf(fmaxf(r1.E, 0.0f), 1.0f); \
            const float v2 = fminf(fmaxf(r2.E, 0.0f), 1.0f); \
            W4.E = __builtin_amdgcn_sqrtf(fmaf(v0, v0, fmaf(v1, v1, fmaf(v2, v2, EPSF)))); \
            const float lg0 = __builtin_amdgcn_logf(v0 + EPSF); \
            const float lg1 = __builtin_amdgcn_logf(v1 + EPSF); \
            const float lg2 = __builtin_amdgcn_logf(v2 + EPSF); \
            float U, V; \
            if (c == 0)      { U = lg0 - lg1; V = lg0 - lg2; } \
            else if (c == 1) { U = lg1 - lg0; V = lg1 - lg2; } \
            else             { U = lg2 - lg0; V = lg2 - lg1; } \
            U4.E = LN2_50 * U; V4.E = LN2_50 * V; }
        PREP(x) PREP(y) PREP(z) PREP(w)
        #undef PREP
        *(h4*)&sUh[ploc] = h4{(_Float16)U4.x, (_Float16)U4.y, (_Float16)U4.z, (_Float16)U4.w};
        *(h4*)&sVh[ploc] = h4{(_Float16)V4.x, (_Float16)V4.y, (_Float16)V4.z, (_Float16)V4.w};
        *(h4*)&sWh[ploc] = h4{(_Float16)W4.x, (_Float16)W4.y, (_Float16)W4.z, (_Float16)W4.w};
    }
    __syncthreads();

    // ---- Phase 2: packed-fp16 eval + MFMA over this wave's 512-px slice ----
    const float step50 = 50.0f * (6.0f / 63.0f);
    const float ou0 = -150.0f + step50 * (float)ln;
    const float ou1 = ou0 + step50 * 32.0f;
    const h2 o0_2 = {(_Float16)ou0, (_Float16)ou0};
    const h2 o1_2 = {(_Float16)ou1, (_Float16)ou1};
    const h2 one2   = {(_Float16)1.0f, (_Float16)1.0f};
    const h2 two2   = {(_Float16)2.0f, (_Float16)2.0f};
    const h2 clamp2 = {(_Float16)16384.0f, (_Float16)16384.0f};
    const s2 magic2 = {(short)0x779A, (short)0x779A};

    f32x16 acc00, acc01, acc10, acc11;
    #pragma unroll
    for (int i = 0; i < 16; i++) { acc00[i] = 0.f; acc01[i] = 0.f; acc10[i] = 0.f; acc11[i] = 0.f; }

    const int wbase = wv * 512;
    #pragma unroll 2
    for (int ks = 0; ks < 32; ks++) {
        const int kb = wbase + ks * 16 + hf * 8;     // half-wave's 8 k-pixels
        H8p U, V, W, A0, A1, B0, B1;
        U.v8 = *(const h8*)&sUh[kb];
        V.v8 = *(const h8*)&sVh[kb];
        W.v8 = *(const h8*)&sWh[kb];
        #pragma unroll
        for (int q = 0; q < 4; q++) {
            A0.h[q] = W.h[q] * kev2(U.h[q], o0_2, one2, two2, clamp2, magic2);
            A1.h[q] = W.h[q] * kev2(U.h[q], o1_2, one2, two2, clamp2, magic2);
            B0.h[q] = kev2(V.h[q], o0_2, one2, two2, clamp2, magic2);
            B1.h[q] = kev2(V.h[q], o1_2, one2, two2, clamp2, magic2);
        }
        acc00 = MFMA(A0.v8, B0.v8, acc00);
        acc01 = MFMA(A0.v8, B1.v8, acc01);
        acc10 = MFMA(A1.v8, B0.v8, acc10);
        acc11 = MFMA(A1.v8, B1.v8, acc11);
    }

    // merge 16 wave accumulators (C/D layout: col=ln, row=(r&3)+8*(r>>2)+4*hf)
    #pragma unroll
    for (int r = 0; r < 16; r++) {
        const int row = (r & 3) + 8 * (r >> 2) + 4 * hf;
        atomicAdd(&sHist[row * 64 + ln],             acc00[r]);
        atomicAdd(&sHist[row * 64 + 32 + ln],        acc01[r]);
        atomicAdd(&sHist[(row + 32) * 64 + ln],      acc10[r]);
        atomicAdd(&sHist[(row + 32) * 64 + 32 + ln], acc11[r]);
    }
    __syncthreads();

    if (atomic_mode == 0) {
        // plain coalesced partial store: partial[chunk][lc][4096]
        float* __restrict__ g = dst + (size_t)(blockIdx.x * LC + lc) * (H * H);
        *(float4*)&g[tid * 4] = *(const float4*)&sHist[tid * 4];
    } else {
        float* __restrict__ g = dst + (size_t)lc * (H * H);
        #pragma unroll
        for (int r = 0; r < 4; r++) {
            const int i = r * 1024 + tid;
            unsafeAtomicAdd(&g[i], sHist[i]);
        }
    }
}

// out[lc][i] = sum of 8 chunk-partials; also per-(lc,seg) sums for norm
__global__ __launch_bounds__(256) void hist_reduce(const float* __restrict__ part,
                                                   float* __restrict__ out,
                                                   float* __restrict__ sums) {
    const int lc  = blockIdx.x >> 4;
    const int seg = blockIdx.x & 15;
    const int i   = lc * (H * H) + seg * 256 + threadIdx.x;
    float s = 0.0f;
    #pragma unroll
    for (int sc = 0; sc < N_CHUNKS; sc++)
        s += part[(size_t)sc * (LC * H * H) + i];
    out[i] = s;
    float t = s;
    #pragma unroll
    for (int o = 32; o > 0; o >>= 1) t += __shfl_down(t, o, 64);
    __shared__ float ps[4];
    if ((threadIdx.x & 63) == 0) ps[threadIdx.x >> 6] = t;
    __syncthreads();
    if (threadIdx.x == 0) sums[blockIdx.x] = (ps[0] + ps[1]) + (ps[2] + ps[3]);
}

// wide normalize: sample l's total = sum of its 48 (lc,seg) sums
__global__ __launch_bounds__(256) void hist_norm(float* __restrict__ out,
                                                 const float* __restrict__ sums) {
    const int i = blockIdx.x * 256 + threadIdx.x;
    const int l = blockIdx.x / 48;
    float T = 0.0f;
    #pragma unroll
    for (int k = 0; k < 48; k++) T += sums[l * 48 + k];
    out[i] = out[i] / (T + EPSF);
}

// fallback finish (atomic path): one block per sample
__global__ __launch_bounds__(256) void hist_finish(float* __restrict__ out) {
    const int l = blockIdx.x;
    float* __restrict__ p = out + l * 3 * H * H;
    float s = 0.0f;
    #pragma unroll
    for (int it = 0; it < 12; it++) {
        const float4 v = *(const float4*)&p[(it * 256 + threadIdx.x) * 4];
        s += (v.x + v.y) + (v.z + v.w);
    }
    #pragma unroll
    for (int off = 32; off > 0; off >>= 1) s += __shfl_down(s, off, 64);
    __shared__ float ps[4];
    if ((threadIdx.x & 63) == 0) ps[threadIdx.x >> 6] = s;
    __syncthreads();
    const float T = (ps[0] + ps[1]) + (ps[2] + ps[3]);
    const float inv = 1.0f / (T + EPSF);
    #pragma unroll
    for (int it = 0; it < 12; it++) {
        float4 v = *(const float4*)&p[(it * 256 + threadIdx.x) * 4];
        v.x *= inv; v.y *= inv; v.z *= inv; v.w *= inv;
        *(float4*)&p[(it * 256 + threadIdx.x) * 4] = v;
    }
}

extern "C" void kernel_launch(void* const* d_in, const int* in_sizes, int n_in,
                              void* d_out, int out_size, void* d_ws, size_t ws_size,
                              hipStream_t stream) {
    const float* x = (const float*)d_in[0];
    float* out = (float*)d_out;
    float* ws  = (float*)d_ws;

    if (ws_size >= NEED_WS) {
        float* sums = ws + WS_PART;
        hipLaunchKernelGGL(hist_main,   dim3(N_CHUNKS, LC),     dim3(1024), 0, stream, x, ws, 0);
        hipLaunchKernelGGL(hist_reduce, dim3(LC * 16),          dim3(256),  0, stream, ws, out, sums);
        hipLaunchKernelGGL(hist_norm,   dim3(LC * H * H / 256), dim3(256),  0, stream, out, sums);
    } else {
        hipLaunchKernelGGL(hist_zero,   dim3(LC * H * H / 256), dim3(256),  0, stream, out);
        hipLaunchKernelGGL(hist_main,   dim3(N_CHUNKS, LC),     dim3(1024), 0, stream, x, out, 1);
        hipLaunchKernelGGL(hist_finish, dim3(LBATCH),           dim3(256),  0, stream, out);
    }
}